// Round 6
// baseline (90.009 us; speedup 1.0000x reference)
//
#include <hip/hip_runtime.h>
#include <math.h>

#define NBATCH 4
#define NANCH  460800
#define NGT    20
#define IMGW   1024.0f
#define IMGH   800.0f
#define POS_THR 0.7f
#define NEG_THR 0.3f
#define NPOS   16
#define NNEG   256
#define CAP    2048          // candidate cap per batch (pow2)
#define NOISE_T 0.998f       // negative-candidate noise threshold (~700 expected)
#define VPT    4             // anchors per thread in assign
#define BLK_ANCH (256 * VPT) // 1024 anchors per block

__device__ __forceinline__ float softplusf(float x) {
    return fmaxf(x, 0.f) + log1pf(expf(-fabsf(x)));
}
__device__ __forceinline__ float smoothl1(float d) {
    float ad = fabsf(d);
    return ad < 1.f ? 0.5f * d * d : ad - 0.5f;
}

// async global->LDS staging (wave-uniform LDS base + lane*size; per-lane gaddr)
__device__ __forceinline__ void stage16(const float* g, float* l) {
    __builtin_amdgcn_global_load_lds(
        (const __attribute__((address_space(1))) void*)g,
        (__attribute__((address_space(3))) void*)l, 16, 0, 0);
}
__device__ __forceinline__ void stage4(const float* g, float* l) {
    __builtin_amdgcn_global_load_lds(
        (const __attribute__((address_space(1))) void*)g,
        (__attribute__((address_space(3))) void*)l, 4, 0, 0);
}

// Full-precision anchor regen (matches reference construction; used in the
// tiny loss path only; assign uses the per-block LDS (w,h) table instead).
__device__ __forceinline__ float4 anchor_from_index(unsigned iu) {
    const float s0 = __int_as_float(0x3F3504F3);  // sqrtf(0.5f)
    const float s2 = __int_as_float(0x3FB504F3);  // sqrtf(2.0f)
    const unsigned hw = iu / 9u, a9 = iu % 9u;
    const unsigned sidx = a9 / 3u, r = a9 % 3u;
    const float scale = (float)(32u << sidx);
    const float sq = (r == 0u) ? s0 : ((r == 1u) ? 1.0f : s2);
    const float w = scale * sq;
    const float h = scale / sq;                    // IEEE division
    const float cx = ((float)(hw & 255u) + 0.5f) * 4.0f;
    const float cy = ((float)(hw >> 8)   + 0.5f) * 4.0f;
    return make_float4(cx - 0.5f * w, cy - 0.5f * h, cx + 0.5f * w, cy + 0.5f * h);
}

// ---------------------------------------------------------------- assign ----
__global__ __launch_bounds__(256) void assign_kernel(
    const float* __restrict__ locs,      // [B,N,4]
    const float* __restrict__ noise,     // [B,N]
    const float* __restrict__ gt,        // [B,M,4]
    float* __restrict__ prop,            // d_out + 2  (8B aligned only!)
    int* __restrict__ pos_cnt, int* __restrict__ negc_cnt,
    int* __restrict__ neg_total,
    float2* __restrict__ pos_buf, float2* __restrict__ neg_buf,
    float* __restrict__ out01)
{
    const int b = blockIdx.y;
    const int t = threadIdx.x;
    __shared__ float4 s_locs[BLK_ANCH];   // 16 KB
    __shared__ float  s_nz[BLK_ANCH];     // 4 KB
    __shared__ float2 s_wh[9];
    __shared__ int s_neg;

    if (t == 0) s_neg = 0;
    if (t < 9) {  // (w,h) per anchor-shape; same ops/rounding as reference
        const float s0 = __int_as_float(0x3F3504F3);
        const float s2 = __int_as_float(0x3FB504F3);
        const unsigned sidx = (unsigned)t / 3u, r = (unsigned)t % 3u;
        const float scale = (float)(32u << sidx);
        const float sq = (r == 0u) ? s0 : ((r == 1u) ? 1.0f : s2);
        s_wh[t] = make_float2(scale * sq, scale / sq);
    }
    if (blockIdx.x == 0 && b == 0 && t < 2) out01[t] = 0.f;
    __syncthreads();   // table visible; nothing significant outstanding yet

    const int blockstart = blockIdx.x * BLK_ANCH;
    const int lane = t & 63, wv = t >> 6;

    // ---- issue async staging: locs 16x1KB chunks, noise 16x256B chunks ----
    #pragma unroll
    for (int q = 0; q < 4; q++) {
        const int c = q * 4 + wv;                       // chunk, uniform per wave
        const size_t gi = (size_t)b * NANCH + blockstart + c * 64 + lane;
        stage16(locs + gi * 4, (float*)s_locs + (size_t)c * 64 * 4);
        stage4 (noise + gi,    s_nz + c * 64);
    }

    // ---- gt boxes (uniform -> scalar regs) ----
    const float4* gtb = (const float4*)gt + b * NGT;
    float4 gb[NGT];
    #pragma unroll
    for (int m = 0; m < NGT; m++) gb[m] = gtb[m];

    // ---- analytic anchors via table ----
    float4 aa[VPT]; float area[VPT]; float msk[VPT];
    #pragma unroll
    for (int k = 0; k < VPT; k++) {
        const unsigned i = (unsigned)(blockstart + t + 256 * k);
        const unsigned hw = i / 9u, a9 = i % 9u;
        const float2 wh = s_wh[a9];
        const float cx = ((float)(hw & 255u) + 0.5f) * 4.0f;
        const float cy = ((float)(hw >> 8)   + 0.5f) * 4.0f;
        aa[k] = make_float4(cx - 0.5f * wh.x, cy - 0.5f * wh.y,
                            cx + 0.5f * wh.x, cy + 0.5f * wh.y);
        area[k] = (aa[k].z - aa[k].x) * (aa[k].w - aa[k].y);
        const bool ins = (aa[k].x >= 0.f) & (aa[k].y >= 0.f) &
                         (aa[k].z <= IMGW) & (aa[k].w <= IMGH);
        msk[k] = ins ? 1.f : 0.f;
    }

    // ---- IoU sweep (overlaps the staging DMA) ----
    float sp[VPT], sn[VPT];
    #pragma unroll
    for (int k = 0; k < VPT; k++) { sp[k] = -1e30f; sn[k] = -1e30f; }
    #pragma unroll
    for (int m = 0; m < NGT; m++) {
        const float bx0 = gb[m].x, by0 = gb[m].y, bx1 = gb[m].z, by1 = gb[m].w;
        const float ab = (bx1 - bx0) * (by1 - by0);
        #pragma unroll
        for (int k = 0; k < VPT; k++) {
            const float lx = fmaxf(aa[k].x, bx0), ly = fmaxf(aa[k].y, by0);
            const float rx = fminf(aa[k].z, bx1), ry = fminf(aa[k].w, by1);
            const float w = fmaxf(rx - lx, 0.f), h = fmaxf(ry - ly, 0.f);
            const float inter = w * h;
            const float uni = area[k] + ab - inter;
            sp[k] = fmaxf(sp[k], fmaf(-POS_THR, uni, inter));
            sn[k] = fmaxf(sn[k], fmaf(-NEG_THR, uni, inter));
        }
    }

    // ---- staged data ready? (per-wave drain, then cross-wave barrier) ----
    asm volatile("s_waitcnt vmcnt(0)" ::: "memory");
    __syncthreads();

    // ---- labels, candidate emission, decode, store ----
    int negc = 0;
    #pragma unroll
    for (int k = 0; k < VPT; k++) {
        const int j = t + 256 * k;            // local anchor
        const int i = blockstart + j;         // global anchor
        const bool inside = (msk[k] != 0.f);
        const bool pos = inside & (sp[k] >= 0.f);
        const bool neg = inside & (sn[k] < 0.f);      // sn<0 => sp<0
        negc += neg ? 1 : 0;

        const float nzv = s_nz[j];
        if (pos) {
            int p = atomicAdd(&pos_cnt[b], 1);            // rare
            if (p < CAP) pos_buf[b * CAP + p] = make_float2(nzv, __int_as_float(i));
        } else if (neg && nzv >= NOISE_T) {
            int p = atomicAdd(&negc_cnt[b], 1);           // ~700/batch expected
            if (p < CAP) neg_buf[b * CAP + p] = make_float2(nzv, __int_as_float(i));
        }

        const float4 dlv = s_locs[j];
        const float aw = aa[k].z - aa[k].x, ah = aa[k].w - aa[k].y;
        const float ax = aa[k].x + 0.5f * aw, ay = aa[k].y + 0.5f * ah;
        const float cx = dlv.x * aw + ax, cy = dlv.y * ah + ay;
        const float w2 = 0.5f * expf(dlv.z) * aw, h2 = 0.5f * expf(dlv.w) * ah;
        float2* o = (float2*)(prop + ((size_t)b * NANCH + i) * 4);
        o[0] = make_float2((cx - w2) * msk[k], (cy - h2) * msk[k]);
        o[1] = make_float2((cx + w2) * msk[k], (cy + h2) * msk[k]);
    }

    // ---- wave reduce negatives, one atomic per block ----
    #pragma unroll
    for (int off = 32; off; off >>= 1) negc += __shfl_xor(negc, off);
    if ((t & 63) == 0 && negc) atomicAdd(&s_neg, negc);
    __syncthreads();
    if (t == 0 && s_neg) atomicAdd(&neg_total[b], s_neg);   // 1 atomic/block
}

// ----------------------------------------------------- fused select+loss ----
// grid (NBATCH, 2): y==0 -> positives (K=16), y==1 -> negatives (K=256).
// Top-K membership via rank-by-counting (keys unique); selected threads
// compute loss terms; block-reduce; one atomicAdd per block.
__global__ __launch_bounds__(1024) void select_loss_kernel(
    const float* __restrict__ locs, const float* __restrict__ scores,
    const float* __restrict__ gt,
    const float2* __restrict__ pos_buf, const float2* __restrict__ neg_buf,
    const int* __restrict__ pos_cnt, const int* __restrict__ negc_cnt,
    const int* __restrict__ neg_total,
    float* __restrict__ out)
{
    __shared__ unsigned long long key[CAP];   // 16 KB
    __shared__ float sl[16], sc[16];
    const int b = blockIdx.x;
    const bool isPos = (blockIdx.y == 0);
    const int t = threadIdx.x;
    const float2* buf = (isPos ? pos_buf : neg_buf) + b * CAP;
    const int K = isPos ? NPOS : NNEG;
    const int n = min(isPos ? pos_cnt[b] : negc_cnt[b], CAP);

    for (int j = t; j < n; j += 1024) {
        float2 c = buf[j];
        key[j] = ((unsigned long long)(unsigned)__float_as_int(c.x) << 32)
               | (unsigned)__float_as_int(c.y);
    }
    __syncthreads();

    int npos = 0, nneg = 0;
    #pragma unroll
    for (int bb = 0; bb < NBATCH; bb++) {
        npos += min(pos_cnt[bb], NPOS);
        nneg += min(neg_total[bb], NNEG);
    }
    const float npd = fmaxf((float)npos, 1.f);
    const float ncd = fmaxf((float)(npos + nneg), 1.f);

    float loc = 0.f, cls = 0.f;
    #pragma unroll
    for (int o = 0; o < CAP / 1024; o++) {
        const int j = t + o * 1024;
        if (j < n) {
            const unsigned long long mykey = key[j];
            int rank = 0;
            for (int k = 0; k < n; k++) rank += (key[k] > mykey) ? 1 : 0;
            if (rank < K) {
                const int i = (int)(unsigned)(mykey & 0xffffffffu);
                if (isPos) {
                    const float4 a = anchor_from_index((unsigned)i);
                    const float area_a = (a.z - a.x) * (a.w - a.y);
                    float best = -1.f; int bm = 0;
                    for (int m = 0; m < NGT; m++) {
                        const float bx0 = gt[(b*NGT+m)*4+0], by0 = gt[(b*NGT+m)*4+1];
                        const float bx1 = gt[(b*NGT+m)*4+2], by1 = gt[(b*NGT+m)*4+3];
                        const float lx = fmaxf(a.x, bx0), ly = fmaxf(a.y, by0);
                        const float rx = fminf(a.z, bx1), ry = fminf(a.w, by1);
                        const float w = fmaxf(rx - lx, 0.f), h = fmaxf(ry - ly, 0.f);
                        const float inter = w * h;
                        const float iou = inter / (area_a + (bx1-bx0)*(by1-by0) - inter);
                        if (iou > best) { best = iou; bm = m; }
                    }
                    const float gx0 = gt[(b*NGT+bm)*4+0], gy0 = gt[(b*NGT+bm)*4+1];
                    const float gx1 = gt[(b*NGT+bm)*4+2], gy1 = gt[(b*NGT+bm)*4+3];
                    const float gw = gx1 - gx0, gh = gy1 - gy0;
                    const float gcx = gx0 + 0.5f * gw, gcy = gy0 + 0.5f * gh;
                    const float aw = a.z - a.x, ah = a.w - a.y;
                    const float ax = a.x + 0.5f * aw, ay = a.y + 0.5f * ah;
                    const float tx = (gcx - ax) / aw, ty = (gcy - ay) / ah;
                    const float tw = logf(gw / aw),  th = logf(gh / ah);
                    const float4 p = ((const float4*)locs)[(size_t)b * NANCH + i];
                    loc += smoothl1(p.x - tx) + smoothl1(p.y - ty)
                         + smoothl1(p.z - tw) + smoothl1(p.w - th);
                    const float s = scores[(size_t)b * NANCH + i];
                    cls += softplusf(s) - s;        // BCE(y=1)
                } else {
                    cls += softplusf(scores[(size_t)b * NANCH + i]);  // BCE(y=0)
                }
            }
        }
    }

    #pragma unroll
    for (int off = 32; off; off >>= 1) {
        loc += __shfl_xor(loc, off);
        cls += __shfl_xor(cls, off);
    }
    if ((t & 63) == 0) { sl[t >> 6] = loc; sc[t >> 6] = cls; }
    __syncthreads();
    if (t == 0) {
        float L = 0.f, C = 0.f;
        #pragma unroll
        for (int w = 0; w < 16; w++) { L += sl[w]; C += sc[w]; }
        if (isPos) atomicAdd(out + 0, L / npd);
        atomicAdd(out + 1, C / ncd);
    }
}

// ---------------------------------------------------------------- launch ----
extern "C" void kernel_launch(void* const* d_in, const int* in_sizes, int n_in,
                              void* d_out, int out_size, void* d_ws, size_t ws_size,
                              hipStream_t stream)
{
    const float* locs    = (const float*)d_in[1];
    const float* scores  = (const float*)d_in[2];
    const float* gt      = (const float*)d_in[3];
    const float* noise   = (const float*)d_in[4];
    float* out = (float*)d_out;

    char* ws = (char*)d_ws;
    int* pos_cnt   = (int*)(ws + 0);     // [4]
    int* negc_cnt  = (int*)(ws + 16);    // [4]
    int* neg_total = (int*)(ws + 32);    // [4]
    float2* pos_buf = (float2*)(ws + 8192);            // 4*2048*8 = 64KB
    float2* neg_buf = (float2*)(ws + 8192 + 65536);    // 64KB

    hipMemsetAsync(ws, 0, 48, stream);   // zero the counter arrays

    dim3 g(NANCH / BLK_ANCH, NBATCH);    // 450 x 4
    assign_kernel<<<g, 256, 0, stream>>>(locs, noise, gt, out + 2,
                                         pos_cnt, negc_cnt, neg_total,
                                         pos_buf, neg_buf, out);
    select_loss_kernel<<<dim3(NBATCH, 2), 1024, 0, stream>>>(
        locs, scores, gt, pos_buf, neg_buf,
        pos_cnt, negc_cnt, neg_total, out);
}